// Round 8
// baseline (158.374 us; speedup 1.0000x reference)
//
#include <hip/hip_runtime.h>
#include <hip/hip_fp16.h>

typedef _Float16 f16;
typedef _Float16 f16x4 __attribute__((ext_vector_type(4)));
typedef _Float16 f16x8 __attribute__((ext_vector_type(8)));
typedef float f32x4 __attribute__((ext_vector_type(4)));

#define GLB_AS __attribute__((address_space(1)))
#define LDS_AS __attribute__((address_space(3)))

// async global->LDS, 16B per lane, dest = wave-uniform base + lane*16
__device__ __forceinline__ void gload_lds16(const f16* g, f16* lds) {
    __builtin_amdgcn_global_load_lds((const GLB_AS uint32_t*)g,
                                     (LDS_AS uint32_t*)lds, 16, 0, 0);
}

// swizzled LDS offset (f16 units) for 128B rows: 16B chunk c8 of row r lives at slot c8^(r&7)
__device__ __forceinline__ int swz(int r, int c8) {
    return r * 64 + (((c8) ^ (r & 7)) << 3);
}

// ---------------- fused fp32 -> fp16 convert (hs + 3 weights) ----------------
__global__ void cvt_all(const float* __restrict__ hs, const float* __restrict__ wq,
                        const float* __restrict__ wk, const float* __restrict__ wv,
                        f16* __restrict__ hs16, f16* __restrict__ w16) {
    int i = blockIdx.x * 256 + threadIdx.x;   // exactly 2015232 threads
    const float4* src;
    f16x4* dst;
    int off;
    if (i < 1572864) {
        src = (const float4*)hs; dst = (f16x4*)hs16; off = i;
    } else {
        int j = i - 1572864;
        int w = j / 147456;
        off = j - w * 147456;
        src = (const float4*)(w == 0 ? wq : (w == 1 ? wk : wv));
        dst = (f16x4*)(w16 + (size_t)w * 589824);
    }
    float4 v = src[off];
    f16x4 h = {(f16)v.x, (f16)v.y, (f16)v.z, (f16)v.w};
    dst[off] = h;
}

// ---------------- QKV GEMM ----------------
// A: hs16 [8192][768]  W: [2304][768] (Wq|Wk|Wv rows)
// out: Q [96][1024][64] (scaled by 0.125*log2e), K [96][1024][64], Vt [96][64][1024]
#define QSCALE 0.18033688011112043f

__global__ __launch_bounds__(256, 4) void qkv_gemm(
        const f16* __restrict__ A, const f16* __restrict__ W,
        f16* __restrict__ Qh, f16* __restrict__ Kh, f16* __restrict__ Vth) {
    __shared__ f16 As[128 * 64];
    __shared__ f16 Bs[128 * 64];
    const int m0 = blockIdx.x * 128;
    const int n0 = blockIdx.y * 128;
    const int tid = threadIdx.x;
    const int wave = tid >> 6, lane = tid & 63;
    const int wm = wave & 1, wn = wave >> 1;
    const int quad = lane >> 4, l16 = lane & 15;
    const int srow = lane >> 3;                    // row-in-inst 0..7
    const int scol = (((lane & 7) ^ srow) << 3);   // swizzled source col (f16)

    f32x4 acc[4][4] = {};

    const f16* Abase = A + (size_t)m0 * 768;
    const f16* Wbase = W + (size_t)n0 * 768;

    for (int kt = 0; kt < 12; ++kt) {
        const int k0 = kt * 64;
        __syncthreads();
#pragma unroll
        for (int j = 0; j < 4; ++j) {
            int inst = wave * 4 + j;           // 16 insts cover 128 rows x 128B
            int row = inst * 8 + srow;
            gload_lds16(Abase + (size_t)row * 768 + k0 + scol, &As[inst * 512]);
            gload_lds16(Wbase + (size_t)row * 768 + k0 + scol, &Bs[inst * 512]);
        }
        __syncthreads();
#pragma unroll
        for (int kk = 0; kk < 2; ++kk) {
            f16x8 af[4], bf[4];
#pragma unroll
            for (int mi = 0; mi < 4; ++mi) {
                int r = wm * 64 + mi * 16 + l16;
                af[mi] = *(const f16x8*)&As[swz(r, kk * 4 + quad)];
            }
#pragma unroll
            for (int ni = 0; ni < 4; ++ni) {
                int r = wn * 64 + ni * 16 + l16;
                bf[ni] = *(const f16x8*)&Bs[swz(r, kk * 4 + quad)];
            }
#pragma unroll
            for (int mi = 0; mi < 4; ++mi)
#pragma unroll
                for (int ni = 0; ni < 4; ++ni)
                    acc[mi][ni] = __builtin_amdgcn_mfma_f32_16x16x32_f16(
                        af[mi], bf[ni], acc[mi][ni], 0, 0, 0);
        }
    }

    // epilogue: seg 0->Q (scaled), 1->K, 2->V written transposed [b,h,d,s]
    const int seg = n0 / 768;
    const int obase = n0 - seg * 768;
    const float scale = (seg == 0) ? QSCALE : 1.0f;
#pragma unroll
    for (int mi = 0; mi < 4; ++mi) {
#pragma unroll
        for (int ni = 0; ni < 4; ++ni) {
            int o = obase + wn * 64 + ni * 16 + l16;
            int h = o >> 6, d = o & 63;
            if (seg == 2) {
                // V: r -> consecutive s, pack 4 f16 into one b64 store
                int gm0 = m0 + wm * 64 + mi * 16 + quad * 4;
                int b = gm0 >> 10, s = gm0 & 1023;
                size_t bh = (size_t)(b * 12 + h);
                f16x4 v4 = {(f16)acc[mi][ni][0], (f16)acc[mi][ni][1],
                            (f16)acc[mi][ni][2], (f16)acc[mi][ni][3]};
                *(f16x4*)&Vth[(bh << 16) + ((size_t)d << 10) + s] = v4;
            } else {
                f16* dst = (seg == 0) ? Qh : Kh;
#pragma unroll
                for (int r = 0; r < 4; ++r) {
                    int gm = m0 + wm * 64 + mi * 16 + quad * 4 + r;
                    int b = gm >> 10, s = gm & 1023;
                    size_t bh = (size_t)(b * 12 + h);
                    dst[((bh << 10 | s) << 6) + d] = (f16)(acc[mi][ni][r] * scale);
                }
            }
        }
    }
}

// ---------------- flash attention: 2q x 2k wave split, register-direct P -------
// wave = (qh = wave>>1, ks = wave&1). Each wave: 2 q-tiles (qh*32..+31) x 32-wide
// k-slice (ks*32..). St = MFMA(A=K_slice, B=Q): lane -> (q=l16, k=quad*4+r), which
// IS the A-layout of mfma_16x16x16f16 -> P stays in registers. Cross-k-slice O
// reduction through dead LDS (Qs/Ks[0]/Vts[0]) at the end; max-free softmax makes
// partials additive. Block = 64 q rows; grid (96,16) = 1536 blocks.
// LDS 40960B x 4 blocks/CU = exactly 160 KiB.
__global__ __launch_bounds__(256, 4) void attn(
        const f16* __restrict__ Qh, const f16* __restrict__ Kh,
        const f16* __restrict__ Vth, float* __restrict__ out) {
    __shared__ __align__(16) char smem[40960];
    f16* Qs  = (f16*)smem;                   // 8KB (64q x 64d, swizzled)
    f16* Ks  = (f16*)(smem + 8192);          // 2 x 8KB (64k x 64d, swizzled)
    f16* Vts = (f16*)(smem + 24576);         // 2 x 8KB (64d x 64k, swizzled)
    float* rbuf  = (float*)smem;             // overlay Qs: 64 fp32 (dead post-prologue)
    float* dbuf  = (float*)(smem + 256);     // overlay Qs: 64 fp32
    float* dump0 = (float*)(smem + 8192);    // overlay Ks[0]: qh=0 partner dump (8KB)
    float* dump1 = (float*)(smem + 24576);   // overlay Vts[0]: qh=1 partner dump (8KB)

    const int bh = blockIdx.x;               // b*12+h
    const int q0 = blockIdx.y * 64;
    const int b = bh / 12, hh = bh % 12;
    const int tid = threadIdx.x, wave = tid >> 6, lane = tid & 63;
    const int ks = wave & 1, qh = wave >> 1;
    const int quad = lane >> 4, l16 = lane & 15;
    const int srow = lane >> 3;
    const int scol = (((lane & 7) ^ srow) << 3);

    const f16* qbase = Qh + ((size_t)bh * 1024 + q0) * 64;
    const f16* kbase = Kh + (size_t)bh * 1024 * 64;
    const f16* vtbase = Vth + (size_t)bh * 64 * 1024;

    // prologue staging: Q + K/V block 0
#pragma unroll
    for (int j = 0; j < 2; ++j) {
        int inst = wave * 2 + j;
        int row = inst * 8 + srow;
        gload_lds16(qbase + row * 64 + scol, &Qs[inst * 512]);
        gload_lds16(kbase + (size_t)row * 64 + scol, &Ks[inst * 512]);
        gload_lds16(vtbase + (size_t)row * 1024 + scol, &Vts[inst * 512]);
    }
    __syncthreads();

    // Q fragments (B-operand): q = qh*32 + t*16 + l16, d-chunk = kk*4+quad
    f16x8 qf[2][2];
#pragma unroll
    for (int t = 0; t < 2; ++t)
#pragma unroll
        for (int kk = 0; kk < 2; ++kk)
            qf[t][kk] = *(const f16x8*)&Qs[swz(qh * 32 + t * 16 + l16, kk * 4 + quad)];

    f32x4 o_acc[2][4] = {};       // [q-tile][d-ct], partial over this wave's k-slice
    float rs[2] = {0.f, 0.f};

    for (int kb = 0; kb < 16; ++kb) {
        const int cur = kb & 1;
        if (kb < 15) {
            const int nk0 = (kb + 1) * 64;
#pragma unroll
            for (int j = 0; j < 2; ++j) {
                int inst = wave * 2 + j;
                int row = inst * 8 + srow;
                gload_lds16(kbase + (size_t)(nk0 + row) * 64 + scol,
                            &Ks[(cur ^ 1) * 4096 + inst * 512]);
                gload_lds16(vtbase + (size_t)row * 1024 + nk0 + scol,
                            &Vts[(cur ^ 1) * 4096 + inst * 512]);
            }
        }

        // K A-frags: rows k = ks*32 + kh*16 + l16
        f16x8 af[2][2];
#pragma unroll
        for (int kh = 0; kh < 2; ++kh) {
            af[kh][0] = *(const f16x8*)&Ks[cur * 4096 + swz(ks * 32 + kh * 16 + l16, quad)];
            af[kh][1] = *(const f16x8*)&Ks[cur * 4096 + swz(ks * 32 + kh * 16 + l16, 4 + quad)];
        }
        // V B-frags: row d=ct*16+l16, k = ks*32 + kh*16 + quad*4 (f16x4)
        f16x4 vf[4][2];
#pragma unroll
        for (int ct = 0; ct < 4; ++ct) {
            int r = ct * 16 + l16;
#pragma unroll
            for (int kh = 0; kh < 2; ++kh) {
                int c8 = ks * 4 + kh * 2 + (quad >> 1);
                vf[ct][kh] = *(const f16x4*)&Vts[cur * 4096 + r * 64 +
                                                 ((c8 ^ (r & 7)) << 3) + (quad & 1) * 4];
            }
        }

#pragma unroll
        for (int t = 0; t < 2; ++t)
#pragma unroll
            for (int kh = 0; kh < 2; ++kh) {
                f32x4 st = {};
                st = __builtin_amdgcn_mfma_f32_16x16x32_f16(af[kh][0], qf[t][0], st, 0, 0, 0);
                st = __builtin_amdgcn_mfma_f32_16x16x32_f16(af[kh][1], qf[t][1], st, 0, 0, 0);
                float e0 = __builtin_amdgcn_exp2f(st[0]);
                float e1 = __builtin_amdgcn_exp2f(st[1]);
                float e2 = __builtin_amdgcn_exp2f(st[2]);
                float e3 = __builtin_amdgcn_exp2f(st[3]);
                rs[t] += (e0 + e1) + (e2 + e3);
                f16x4 pv = {(f16)e0, (f16)e1, (f16)e2, (f16)e3};  // A-frag of x16 MFMA
#pragma unroll
                for (int ct = 0; ct < 4; ++ct)
                    o_acc[t][ct] = __builtin_amdgcn_mfma_f32_16x16x16f16(
                        pv, vf[ct][kh], o_acc[t][ct], 0, 0, 0);
            }

        if (kb < 15) __syncthreads();
    }

    // quad-reduce rsum -> this wave's k-slice sum for q = qh*32 + t*16 + l16
    float rt[2];
#pragma unroll
    for (int t = 0; t < 2; ++t) {
        float v = rs[t];
        v += __shfl_xor(v, 16, 64);
        v += __shfl_xor(v, 32, 64);
        rt[t] = v;
    }

    // k-slice 1 waves publish partials into dead LDS (Ks[0]/Vts[0]/Qs regions)
    if (ks == 1) {
        float* dp = qh ? dump1 : dump0;
#pragma unroll
        for (int t = 0; t < 2; ++t)
#pragma unroll
            for (int ct = 0; ct < 4; ++ct)
                *(f32x4*)&dp[(t * 4 + ct) * 256 + lane * 4] = o_acc[t][ct];
        if (quad == 0) {
            rbuf[qh * 32 + l16] = rt[0];
            rbuf[qh * 32 + 16 + l16] = rt[1];
        }
    }
    __syncthreads();
    if (ks == 0) {
        const float* dp = qh ? dump1 : dump0;
#pragma unroll
        for (int t = 0; t < 2; ++t)
#pragma unroll
            for (int ct = 0; ct < 4; ++ct)
                o_acc[t][ct] += *(const f32x4*)&dp[(t * 4 + ct) * 256 + lane * 4];
        // total denominators; dbuf indexed by local q
#pragma unroll
        for (int t = 0; t < 2; ++t) {
            float tot = rt[t] + rbuf[qh * 32 + t * 16 + l16];
            if (quad == 0) dbuf[qh * 32 + t * 16 + l16] = 1.0f / tot;
        }
        // store: D-layout of PV: q = quad*4+r, d = ct*16+l16
#pragma unroll
        for (int t = 0; t < 2; ++t) {
            float di[4];
#pragma unroll
            for (int r = 0; r < 4; ++r)
                di[r] = dbuf[qh * 32 + t * 16 + quad * 4 + r];
#pragma unroll
            for (int ct = 0; ct < 4; ++ct)
#pragma unroll
                for (int r = 0; r < 4; ++r) {
                    int s = q0 + qh * 32 + t * 16 + quad * 4 + r;
                    out[((size_t)b * 1024 + s) * 768 + hh * 64 + ct * 16 + l16] =
                        o_acc[t][ct][r] * di[r];
                }
        }
    }
}

extern "C" void kernel_launch(void* const* d_in, const int* in_sizes, int n_in,
                              void* d_out, int out_size, void* d_ws, size_t ws_size,
                              hipStream_t stream) {
    const float* hs = (const float*)d_in[0];
    const float* Wq = (const float*)d_in[1];
    const float* Wk = (const float*)d_in[2];
    const float* Wv = (const float*)d_in[3];
    float* out = (float*)d_out;

    char* ws = (char*)d_ws;
    f16* hs16 = (f16*)ws;                    // 12582912 B
    f16* w16  = (f16*)(ws + 12582912);       //  3538944 B
    f16* Qh   = (f16*)(ws + 16121856);       // 12582912 B
    f16* Kh   = (f16*)(ws + 28704768);       // 12582912 B
    f16* Vth  = (f16*)(ws + 41287680);       // 12582912 B -> 53.9 MB total

    cvt_all<<<7872, 256, 0, stream>>>(hs, Wq, Wk, Wv, hs16, w16);
    qkv_gemm<<<dim3(64, 18), 256, 0, stream>>>(hs16, w16, Qh, Kh, Vth);
    attn<<<dim3(96, 16), 256, 0, stream>>>(Qh, Kh, Vth, out);
    (void)in_sizes; (void)n_in; (void)out_size; (void)ws_size;
}

// Round 9
// 153.563 us; speedup vs baseline: 1.0313x; 1.0313x over previous
//
#include <hip/hip_runtime.h>
#include <hip/hip_fp16.h>

typedef _Float16 f16;
typedef _Float16 f16x4 __attribute__((ext_vector_type(4)));
typedef _Float16 f16x8 __attribute__((ext_vector_type(8)));
typedef float f32x4 __attribute__((ext_vector_type(4)));

#define GLB_AS __attribute__((address_space(1)))
#define LDS_AS __attribute__((address_space(3)))

// async global->LDS, 16B per lane, dest = wave-uniform base + lane*16
__device__ __forceinline__ void gload_lds16(const f16* g, f16* lds) {
    __builtin_amdgcn_global_load_lds((const GLB_AS uint32_t*)g,
                                     (LDS_AS uint32_t*)lds, 16, 0, 0);
}

// swizzled LDS offset (f16 units) for 128B rows: 16B chunk c8 of row r lives at slot c8^(r&7)
__device__ __forceinline__ int swz(int r, int c8) {
    return r * 64 + (((c8) ^ (r & 7)) << 3);
}

// ---------------- fused fp32 -> fp16 convert (hs + 3 weights) ----------------
__global__ void cvt_all(const float* __restrict__ hs, const float* __restrict__ wq,
                        const float* __restrict__ wk, const float* __restrict__ wv,
                        f16* __restrict__ hs16, f16* __restrict__ w16) {
    int i = blockIdx.x * 256 + threadIdx.x;   // exactly 2015232 threads
    const float4* src;
    f16x4* dst;
    int off;
    if (i < 1572864) {
        src = (const float4*)hs; dst = (f16x4*)hs16; off = i;
    } else {
        int j = i - 1572864;
        int w = j / 147456;
        off = j - w * 147456;
        src = (const float4*)(w == 0 ? wq : (w == 1 ? wk : wv));
        dst = (f16x4*)(w16 + (size_t)w * 589824);
    }
    float4 v = src[off];
    f16x4 h = {(f16)v.x, (f16)v.y, (f16)v.z, (f16)v.w};
    dst[off] = h;
}

// ---------------- QKV GEMM ----------------
// A: hs16 [8192][768]  W: [2304][768] (Wq|Wk|Wv rows)
// out: Q [96][1024][64] (scaled by 0.125*log2e), K [96][1024][64], Vt [96][64][1024]
#define QSCALE 0.18033688011112043f

__global__ __launch_bounds__(256, 4) void qkv_gemm(
        const f16* __restrict__ A, const f16* __restrict__ W,
        f16* __restrict__ Qh, f16* __restrict__ Kh, f16* __restrict__ Vth) {
    __shared__ f16 As[128 * 64];
    __shared__ f16 Bs[128 * 64];
    const int m0 = blockIdx.x * 128;
    const int n0 = blockIdx.y * 128;
    const int tid = threadIdx.x;
    const int wave = tid >> 6, lane = tid & 63;
    const int wm = wave & 1, wn = wave >> 1;
    const int quad = lane >> 4, l16 = lane & 15;
    const int srow = lane >> 3;                    // row-in-inst 0..7
    const int scol = (((lane & 7) ^ srow) << 3);   // swizzled source col (f16)

    f32x4 acc[4][4] = {};

    const f16* Abase = A + (size_t)m0 * 768;
    const f16* Wbase = W + (size_t)n0 * 768;

    for (int kt = 0; kt < 12; ++kt) {
        const int k0 = kt * 64;
        __syncthreads();
#pragma unroll
        for (int j = 0; j < 4; ++j) {
            int inst = wave * 4 + j;           // 16 insts cover 128 rows x 128B
            int row = inst * 8 + srow;
            gload_lds16(Abase + (size_t)row * 768 + k0 + scol, &As[inst * 512]);
            gload_lds16(Wbase + (size_t)row * 768 + k0 + scol, &Bs[inst * 512]);
        }
        __syncthreads();
#pragma unroll
        for (int kk = 0; kk < 2; ++kk) {
            f16x8 af[4], bf[4];
#pragma unroll
            for (int mi = 0; mi < 4; ++mi) {
                int r = wm * 64 + mi * 16 + l16;
                af[mi] = *(const f16x8*)&As[swz(r, kk * 4 + quad)];
            }
#pragma unroll
            for (int ni = 0; ni < 4; ++ni) {
                int r = wn * 64 + ni * 16 + l16;
                bf[ni] = *(const f16x8*)&Bs[swz(r, kk * 4 + quad)];
            }
#pragma unroll
            for (int mi = 0; mi < 4; ++mi)
#pragma unroll
                for (int ni = 0; ni < 4; ++ni)
                    acc[mi][ni] = __builtin_amdgcn_mfma_f32_16x16x32_f16(
                        af[mi], bf[ni], acc[mi][ni], 0, 0, 0);
        }
    }

    // epilogue: seg 0->Q (scaled), 1->K, 2->V written transposed [b,h,d,s]
    const int seg = n0 / 768;
    const int obase = n0 - seg * 768;
    const float scale = (seg == 0) ? QSCALE : 1.0f;
#pragma unroll
    for (int mi = 0; mi < 4; ++mi) {
#pragma unroll
        for (int ni = 0; ni < 4; ++ni) {
            int o = obase + wn * 64 + ni * 16 + l16;
            int h = o >> 6, d = o & 63;
            if (seg == 2) {
                // V: r -> consecutive s, pack 4 f16 into one b64 store
                int gm0 = m0 + wm * 64 + mi * 16 + quad * 4;
                int b = gm0 >> 10, s = gm0 & 1023;
                size_t bh = (size_t)(b * 12 + h);
                f16x4 v4 = {(f16)acc[mi][ni][0], (f16)acc[mi][ni][1],
                            (f16)acc[mi][ni][2], (f16)acc[mi][ni][3]};
                *(f16x4*)&Vth[(bh << 16) + ((size_t)d << 10) + s] = v4;
            } else {
                f16* dst = (seg == 0) ? Qh : Kh;
#pragma unroll
                for (int r = 0; r < 4; ++r) {
                    int gm = m0 + wm * 64 + mi * 16 + quad * 4 + r;
                    int b = gm >> 10, s = gm & 1023;
                    size_t bh = (size_t)(b * 12 + h);
                    dst[((bh << 10 | s) << 6) + d] = (f16)(acc[mi][ni][r] * scale);
                }
            }
        }
    }
}

// ---------------- flash attention: 128-q block, wave = q-slice, full-k ---------
// 4 waves, each handles 2 q-tiles (wave*32..+31) over the FULL 64-k block.
// St = MFMA(A=K, B=Q): lane -> (q=l16, k=quad*4+r) == A-layout of mfma_16x16x16f16
// so P stays in registers. No k-split -> no cross-wave reduction at all.
// Grid (96,8) = 768 blocks = exactly 3 blocks/CU x 256 CUs = ONE dispatch round.
// LDS 48KB x 3 = 144KB/CU. Same-bh blocks land on one XCD (idx%8 = bh%8).
__global__ __launch_bounds__(256, 3) void attn(
        const f16* __restrict__ Qh, const f16* __restrict__ Kh,
        const f16* __restrict__ Vth, float* __restrict__ out) {
    __shared__ __align__(16) char smem[49152];
    f16* Qs  = (f16*)smem;                   // 16KB (128q x 64d, swizzled)
    f16* Ks  = (f16*)(smem + 16384);         // 2 x 8KB (64k x 64d, swizzled)
    f16* Vts = (f16*)(smem + 32768);         // 2 x 8KB (64d x 64k, swizzled)

    const int bh = blockIdx.x;               // b*12+h
    const int q0 = blockIdx.y * 128;
    const int b = bh / 12, hh = bh % 12;
    const int tid = threadIdx.x, wave = tid >> 6, lane = tid & 63;
    const int quad = lane >> 4, l16 = lane & 15;
    const int srow = lane >> 3;
    const int scol = (((lane & 7) ^ srow) << 3);

    const f16* qbase = Qh + ((size_t)bh * 1024 + q0) * 64;
    const f16* kbase = Kh + (size_t)bh * 1024 * 64;
    const f16* vtbase = Vth + (size_t)bh * 64 * 1024;

    // prologue: stage Q (16 insts) + K/V block 0 (8+8 insts)
#pragma unroll
    for (int j = 0; j < 4; ++j) {
        int inst = wave * 4 + j;
        int row = inst * 8 + srow;
        gload_lds16(qbase + row * 64 + scol, &Qs[inst * 512]);
    }
#pragma unroll
    for (int j = 0; j < 2; ++j) {
        int inst = wave * 2 + j;
        int row = inst * 8 + srow;
        gload_lds16(kbase + (size_t)row * 64 + scol, &Ks[inst * 512]);
        gload_lds16(vtbase + (size_t)row * 1024 + scol, &Vts[inst * 512]);
    }
    __syncthreads();

    // Q fragments (B-operand): q = wave*32 + t*16 + l16, d-chunk = kk*4+quad
    f16x8 qf[2][2];
#pragma unroll
    for (int t = 0; t < 2; ++t)
#pragma unroll
        for (int kk = 0; kk < 2; ++kk)
            qf[t][kk] = *(const f16x8*)&Qs[swz(wave * 32 + t * 16 + l16, kk * 4 + quad)];

    f32x4 o_acc[2][4] = {};       // [q-tile][d-ct]
    float rs[2] = {0.f, 0.f};

    for (int kb = 0; kb < 16; ++kb) {
        const int cur = kb & 1;
        if (kb < 15) {
            const int nk0 = (kb + 1) * 64;
#pragma unroll
            for (int j = 0; j < 2; ++j) {
                int inst = wave * 2 + j;
                int row = inst * 8 + srow;
                gload_lds16(kbase + (size_t)(nk0 + row) * 64 + scol,
                            &Ks[(cur ^ 1) * 4096 + inst * 512]);
                gload_lds16(vtbase + (size_t)row * 1024 + nk0 + scol,
                            &Vts[(cur ^ 1) * 4096 + inst * 512]);
            }
        }

        // QK phase: St[t][ct] -> lane holds (q=l16, k=ct*16+quad*4+r)
        f32x4 st[2][4] = {};
#pragma unroll
        for (int ct = 0; ct < 4; ++ct) {
            f16x8 a0 = *(const f16x8*)&Ks[cur * 4096 + swz(ct * 16 + l16, quad)];
            f16x8 a1 = *(const f16x8*)&Ks[cur * 4096 + swz(ct * 16 + l16, 4 + quad)];
#pragma unroll
            for (int t = 0; t < 2; ++t) {
                st[t][ct] = __builtin_amdgcn_mfma_f32_16x16x32_f16(a0, qf[t][0], st[t][ct], 0, 0, 0);
                st[t][ct] = __builtin_amdgcn_mfma_f32_16x16x32_f16(a1, qf[t][1], st[t][ct], 0, 0, 0);
            }
        }

        // exp2 -> P fragments (register-direct A-frags of x16 MFMA)
        f16x4 pv[2][4];
#pragma unroll
        for (int t = 0; t < 2; ++t)
#pragma unroll
            for (int ct = 0; ct < 4; ++ct) {
                float e0 = __builtin_amdgcn_exp2f(st[t][ct][0]);
                float e1 = __builtin_amdgcn_exp2f(st[t][ct][1]);
                float e2 = __builtin_amdgcn_exp2f(st[t][ct][2]);
                float e3 = __builtin_amdgcn_exp2f(st[t][ct][3]);
                rs[t] += (e0 + e1) + (e2 + e3);
                pv[t][ct] = f16x4{(f16)e0, (f16)e1, (f16)e2, (f16)e3};
            }

        // PV phase: O[t][ct] += P[t][kc] * V[kc][ct]
#pragma unroll
        for (int kc = 0; kc < 4; ++kc) {
            f16x4 vf[4];
#pragma unroll
            for (int ct = 0; ct < 4; ++ct) {
                int r = ct * 16 + l16;
                int c8 = kc * 2 + (quad >> 1);
                vf[ct] = *(const f16x4*)&Vts[cur * 4096 + r * 64 +
                                             ((c8 ^ (r & 7)) << 3) + (quad & 1) * 4];
            }
#pragma unroll
            for (int t = 0; t < 2; ++t)
#pragma unroll
                for (int ct = 0; ct < 4; ++ct)
                    o_acc[t][ct] = __builtin_amdgcn_mfma_f32_16x16x16f16(
                        pv[t][kc], vf[ct], o_acc[t][ct], 0, 0, 0);
        }

        if (kb < 15) __syncthreads();
    }

    // epilogue: pure-register denominators, no LDS, no barrier
#pragma unroll
    for (int t = 0; t < 2; ++t) {
        float v = rs[t];
        v += __shfl_xor(v, 16, 64);
        v += __shfl_xor(v, 32, 64);     // lane x: full denom for q-local = wave*32+t*16+(x&15)
        float di[4];
#pragma unroll
        for (int r = 0; r < 4; ++r)
            di[r] = 1.0f / __shfl(v, quad * 4 + r, 64);
#pragma unroll
        for (int ct = 0; ct < 4; ++ct)
#pragma unroll
            for (int r = 0; r < 4; ++r) {
                int s = q0 + wave * 32 + t * 16 + quad * 4 + r;
                out[((size_t)b * 1024 + s) * 768 + hh * 64 + ct * 16 + l16] =
                    o_acc[t][ct][r] * di[r];
            }
    }
}

extern "C" void kernel_launch(void* const* d_in, const int* in_sizes, int n_in,
                              void* d_out, int out_size, void* d_ws, size_t ws_size,
                              hipStream_t stream) {
    const float* hs = (const float*)d_in[0];
    const float* Wq = (const float*)d_in[1];
    const float* Wk = (const float*)d_in[2];
    const float* Wv = (const float*)d_in[3];
    float* out = (float*)d_out;

    char* ws = (char*)d_ws;
    f16* hs16 = (f16*)ws;                    // 12582912 B
    f16* w16  = (f16*)(ws + 12582912);       //  3538944 B
    f16* Qh   = (f16*)(ws + 16121856);       // 12582912 B
    f16* Kh   = (f16*)(ws + 28704768);       // 12582912 B
    f16* Vth  = (f16*)(ws + 41287680);       // 12582912 B -> 53.9 MB total

    cvt_all<<<7872, 256, 0, stream>>>(hs, Wq, Wk, Wv, hs16, w16);
    qkv_gemm<<<dim3(64, 18), 256, 0, stream>>>(hs16, w16, Qh, Kh, Vth);
    attn<<<dim3(96, 8), 256, 0, stream>>>(Qh, Kh, Vth, out);
    (void)in_sizes; (void)n_in; (void)out_size; (void)ws_size;
}